// Round 7
// baseline (581.200 us; speedup 1.0000x reference)
//
#include <hip/hip_runtime.h>
#include <cstddef>

#define B 32
#define T_ENC 512
#define T_DEC 32
#define E 256
#define VOCAB 32000
#define SOS 1
#define NEG2LOG2E -2.885390081777927f   // -2 * log2(e)

typedef __attribute__((ext_vector_type(8))) short short8;   // 8 x bf16
typedef __attribute__((ext_vector_type(4))) float floatx4;  // MFMA acc

// ---------------- workspace layout (float offsets) ----------------
static const size_t OFF_ENCW   = 0;                                    // 8388608: fused [16384][512], PRE-SCALED
static const size_t OFF_WEFFM  = OFF_ENCW + (size_t)B * T_ENC * 2 * E; // 256
static const size_t OFF_WEFFC  = OFF_WEFFM + E;                        // 256
static const size_t OFF_XIH    = OFF_WEFFC + E;                        // 262144
static const size_t OFF_WCOMBT = OFF_XIH + (size_t)T_DEC * B * E;      // 131072
static const size_t OFF_ATTNB  = OFF_WCOMBT + (size_t)2 * E * E;       // 131072 floats (ushort x2)
static const size_t OFF_WPBF   = OFF_ATTNB + (size_t)T_DEC * B * E / 2;// 4096000 floats (ushort x2)

// ---------------- d_out scratch layout (float offsets) ----------------
static const size_t OUT_BETA  = 262144;    // 524288: beta_T[b][t][s]  (TRANSPOSED)
static const size_t OUT_ACOMB = 786432;    // 524288: [ctx | h] rows (b*32+s) x 512
static const size_t OUT_HALL  = 1310720;   // 262144: h[b][s][256]
static const size_t OUT_HV    = 1572864;   // 524288: -2log2e*[hVm | hVc] rows x 512
static const size_t OUT_PE    = 2097152;   // 1048576: g_pe[b][col][t], col = type*32+s
static const size_t OUT_VMC   = 3145728;   // 131072: [Vm ; Vc]
static const size_t OUT_ZERO  = 3276800;   // 512 zeros
static const size_t OUT_WHI   = 3277312;   // 65536 floats = 131072 ushort: W split hi [512][256]
static const size_t OUT_WLO   = 3342848;   // 65536 floats: W split lo
static const size_t OUT_B512  = 3408384;   // 512: [bm ; bc]

// ---------------- helpers ----------------
__device__ __forceinline__ float ftanh(float x) {
  float ax = __builtin_fabsf(x);
  float e  = __expf(-2.f * ax);
  float r  = (1.f - e) * __builtin_amdgcn_rcpf(1.f + e);
  return __builtin_copysignf(r, x);
}

__device__ __forceinline__ float fsigmoid(float z) {
  return __builtin_amdgcn_rcpf(1.f + __expf(-z));
}

__device__ __forceinline__ float wredmax(float s) {
  s = fmaxf(s, __shfl_xor(s, 1, 64));  s = fmaxf(s, __shfl_xor(s, 2, 64));
  s = fmaxf(s, __shfl_xor(s, 4, 64));  s = fmaxf(s, __shfl_xor(s, 8, 64));
  s = fmaxf(s, __shfl_xor(s, 16, 64)); s = fmaxf(s, __shfl_xor(s, 32, 64));
  return s;
}

__device__ __forceinline__ unsigned short f2bf(float f) {
  unsigned int u = __float_as_uint(f);
  u = (u + 0x7fffu + ((u >> 16) & 1u)) >> 16;   // RNE
  return (unsigned short)u;
}

__device__ __forceinline__ float bf2f(unsigned short h) {
  return __uint_as_float((unsigned int)h << 16);
}

// exclusive prefix (across 64 lanes) of per-lane totals
__device__ __forceinline__ float wexcl(float tot, int lane) {
  float v = tot;
#pragma unroll
  for (int off = 1; off < 64; off <<= 1) {
    float y = __shfl_up(v, off, 64);
    if (lane >= off) v += y;
  }
  return v - tot;
}

// sum_i w_i * tanh(x_i); inputs PRE-SCALED by -2*log2(e) AT THE PRODUCER,
// so the hot loop is add + v_exp + fma + rcp + fma -- no scaling ops.
__device__ __forceinline__ float dot4_wtanh(float4 s2a, float4 s2b, float4 w4) {
  float e, num, acc;
  e = __builtin_exp2f(s2a.x + s2b.x); num = __builtin_fmaf(-e, w4.x, w4.x);
  acc = num * __builtin_amdgcn_rcpf(1.f + e);
  e = __builtin_exp2f(s2a.y + s2b.y); num = __builtin_fmaf(-e, w4.y, w4.y);
  acc = __builtin_fmaf(num, __builtin_amdgcn_rcpf(1.f + e), acc);
  e = __builtin_exp2f(s2a.z + s2b.z); num = __builtin_fmaf(-e, w4.z, w4.z);
  acc = __builtin_fmaf(num, __builtin_amdgcn_rcpf(1.f + e), acc);
  e = __builtin_exp2f(s2a.w + s2b.w); num = __builtin_fmaf(-e, w4.w, w4.w);
  acc = __builtin_fmaf(num, __builtin_amdgcn_rcpf(1.f + e), acc);
  return acc;
}

// ---- fused prep: Xih-gemm (gather inline) + weff + biases + Vmc + Wsplit
//      + W_comb transpose + W_proj cvt. One launch; branch by block range.
__global__ __launch_bounds__(256) void prep_all(
    const int* __restrict__ dec, const float* __restrict__ emb,
    const float* __restrict__ W_ih,
    const float* __restrict__ b_ih, const float* __restrict__ b_hh,
    float* __restrict__ Xih,
    const float* __restrict__ vvm, const float* __restrict__ gm, float* __restrict__ w_effm,
    const float* __restrict__ vvc, const float* __restrict__ gc, float* __restrict__ w_effc,
    const float* __restrict__ bm, const float* __restrict__ bc, float* __restrict__ bias512,
    const float* __restrict__ Vm, const float* __restrict__ Vc,
    float* __restrict__ Vmc, float* __restrict__ zero512,
    const float* __restrict__ Wm, const float* __restrict__ Wc,
    unsigned short* __restrict__ Whi, unsigned short* __restrict__ Wlo,
    const float* __restrict__ W_comb, float* __restrict__ W_combT,
    const float* __restrict__ W_proj, unsigned short* __restrict__ Wp_bf)
{
  __shared__ float As[64][68];
  __shared__ float Ws[64][68];
  __shared__ float tl[32][33];
  const int blk = blockIdx.x, tid = threadIdx.x;

  if (blk < 64) {
    // ---- Xih = emb[tok] @ W_ih.T + (b_ih + b_hh), gather inline ----
    const int tx = tid & 15, ty = tid >> 4;
    const int row0 = (blk >> 2) * 64, col0 = (blk & 3) * 64;
    float acc[4][4];
#pragma unroll
    for (int i = 0; i < 4; i++)
#pragma unroll
      for (int j = 0; j < 4; j++) acc[i][j] = 0.f;
    for (int k0 = 0; k0 < E; k0 += 64) {
#pragma unroll
      for (int s = 0; s < 4; s++) {
        int i = (s << 4) + ty;
        int j = tx << 2;
        int r = row0 + i;                      // r = s*B + b (row of Xih)
        int st = r >> 5, bb = r & 31;
        int tok = (st == 0) ? SOS : dec[bb * T_DEC + st - 1];
        float4 av = *(const float4*)(emb + (size_t)tok * E + k0 + j);
        As[j][i] = av.x; As[j + 1][i] = av.y; As[j + 2][i] = av.z; As[j + 3][i] = av.w;
        float4 wv = *(const float4*)(W_ih + (size_t)(col0 + i) * E + k0 + j);
        Ws[j][i] = wv.x; Ws[j + 1][i] = wv.y; Ws[j + 2][i] = wv.z; Ws[j + 3][i] = wv.w;
      }
      __syncthreads();
#pragma unroll
      for (int kk = 0; kk < 64; kk++) {
        const float4 af = *(const float4*)&As[kk][ty << 2];
        const float4 bf = *(const float4*)&Ws[kk][tx << 2];
        acc[0][0] += af.x * bf.x; acc[0][1] += af.x * bf.y; acc[0][2] += af.x * bf.z; acc[0][3] += af.x * bf.w;
        acc[1][0] += af.y * bf.x; acc[1][1] += af.y * bf.y; acc[1][2] += af.y * bf.z; acc[1][3] += af.y * bf.w;
        acc[2][0] += af.z * bf.x; acc[2][1] += af.z * bf.y; acc[2][2] += af.z * bf.z; acc[2][3] += af.z * bf.w;
        acc[3][0] += af.w * bf.x; acc[3][1] += af.w * bf.y; acc[3][2] += af.w * bf.z; acc[3][3] += af.w * bf.w;
      }
      __syncthreads();
    }
    float4 b1 = *(const float4*)(b_ih + col0 + (tx << 2));
    float4 b2 = *(const float4*)(b_hh + col0 + (tx << 2));
#pragma unroll
    for (int i = 0; i < 4; i++) {
      float4 o;
      o.x = acc[i][0] + b1.x + b2.x; o.y = acc[i][1] + b1.y + b2.y;
      o.z = acc[i][2] + b1.z + b2.z; o.w = acc[i][3] + b1.w + b2.w;
      *(float4*)(Xih + (size_t)(row0 + (ty << 2) + i) * E + col0 + (tx << 2)) = o;
    }
  } else if (blk < 66) {
    const int k = blk - 64;
    const float* vv = k ? vvc : vvm;
    const float* g  = k ? gc  : gm;
    float* out      = k ? w_effc : w_effm;
    float v = vv[tid];
    As[0][0] = 0.f;  // (unused)
    __shared__ float red[256];
    red[tid] = v * v;
    __syncthreads();
    for (int off = 128; off > 0; off >>= 1) {
      if (tid < off) red[tid] += red[tid + off];
      __syncthreads();
    }
    float norm = sqrtf(red[0]);
    out[tid] = (g[0] / norm) * v;
  } else if (blk == 66) {
    bias512[tid]       = bm[tid];
    bias512[256 + tid] = bc[tid];
    zero512[tid] = 0.f;
    zero512[256 + tid] = 0.f;
  } else if (blk < 195) {
    int i = (blk - 67) * 1024 + tid * 4;
    float4 v = (i < E * E) ? *(const float4*)(Vm + i) : *(const float4*)(Vc + i - E * E);
    *(float4*)(Vmc + i) = v;
  } else if (blk < 323) {
    int i = (blk - 195) * 1024 + tid * 4;
    float4 v = (i < E * E) ? *(const float4*)(Wm + i) : *(const float4*)(Wc + i - E * E);
    ushort4 h, l;
    h.x = f2bf(v.x); l.x = f2bf(v.x - bf2f(h.x));
    h.y = f2bf(v.y); l.y = f2bf(v.y - bf2f(h.y));
    h.z = f2bf(v.z); l.z = f2bf(v.z - bf2f(h.z));
    h.w = f2bf(v.w); l.w = f2bf(v.w - bf2f(h.w));
    *(ushort4*)(Whi + i) = h;
    *(ushort4*)(Wlo + i) = l;
  } else if (blk < 451) {
    // W_comb [256][512] -> W_combT [512][256]
    int k2 = blk - 323;
    const int bx = k2 & 15, by = k2 >> 4;
    const int tx = tid & 31, ty = tid >> 5;
    const int c0 = bx * 32, r0 = by * 32;
#pragma unroll
    for (int k = 0; k < 4; k++)
      tl[ty + 8 * k][tx] = W_comb[(size_t)(r0 + ty + 8 * k) * 512 + c0 + tx];
    __syncthreads();
#pragma unroll
    for (int k = 0; k < 4; k++)
      W_combT[(size_t)(c0 + ty + 8 * k) * 256 + r0 + tx] = tl[tx][ty + 8 * k];
  } else {
    size_t i = ((size_t)(blk - 451) * 256 + tid) * 4;
    float4 v = *(const float4*)(W_proj + i);
    ushort4 o;
    o.x = f2bf(v.x); o.y = f2bf(v.y); o.z = f2bf(v.z); o.w = f2bf(v.w);
    *(ushort4*)(Wp_bf + i) = o;
  }
}

// ---------------- Y[r,n] = alpha*(bias[n] + sum_k A[r,k]*W[n,k]) ----------
__global__ __launch_bounds__(256) void gemm_xwt(
    const float* __restrict__ A, const float* __restrict__ W,
    const float* __restrict__ bias, float* __restrict__ Y,
    int M, int N, int K, float alpha)
{
  __shared__ float As[64][68];
  __shared__ float Ws[64][68];
  const int tid = threadIdx.x;
  const int tx = tid & 15, ty = tid >> 4;
  const int row0 = blockIdx.y * 64, col0 = blockIdx.x * 64;
  float acc[4][4];
#pragma unroll
  for (int i = 0; i < 4; i++)
#pragma unroll
    for (int j = 0; j < 4; j++) acc[i][j] = 0.f;

  for (int k0 = 0; k0 < K; k0 += 64) {
#pragma unroll
    for (int s = 0; s < 4; s++) {
      int i = (s << 4) + ty;
      int j = tx << 2;
      float4 av = *(const float4*)(A + (size_t)(row0 + i) * K + k0 + j);
      As[j][i] = av.x; As[j + 1][i] = av.y; As[j + 2][i] = av.z; As[j + 3][i] = av.w;
      float4 wv = *(const float4*)(W + (size_t)(col0 + i) * K + k0 + j);
      Ws[j][i] = wv.x; Ws[j + 1][i] = wv.y; Ws[j + 2][i] = wv.z; Ws[j + 3][i] = wv.w;
    }
    __syncthreads();
#pragma unroll
    for (int kk = 0; kk < 64; kk++) {
      const float4 af = *(const float4*)&As[kk][ty << 2];
      const float4 bf = *(const float4*)&Ws[kk][tx << 2];
      acc[0][0] += af.x * bf.x; acc[0][1] += af.x * bf.y; acc[0][2] += af.x * bf.z; acc[0][3] += af.x * bf.w;
      acc[1][0] += af.y * bf.x; acc[1][1] += af.y * bf.y; acc[1][2] += af.y * bf.z; acc[1][3] += af.y * bf.w;
      acc[2][0] += af.z * bf.x; acc[2][1] += af.z * bf.y; acc[2][2] += af.z * bf.z; acc[2][3] += af.z * bf.w;
      acc[3][0] += af.w * bf.x; acc[3][1] += af.w * bf.y; acc[3][2] += af.w * bf.z; acc[3][3] += af.w * bf.w;
    }
    __syncthreads();
  }
  const float4 bv = *(const float4*)(bias + col0 + (tx << 2));
#pragma unroll
  for (int i = 0; i < 4; i++) {
    float4 o;
    o.x = alpha * (acc[i][0] + bv.x); o.y = alpha * (acc[i][1] + bv.y);
    o.z = alpha * (acc[i][2] + bv.z); o.w = alpha * (acc[i][3] + bv.w);
    *(float4*)(Y + (size_t)(row0 + (ty << 2) + i) * N + col0 + (tx << 2)) = o;
  }
}

// ---- FUSED: h-chain (blocks 0..31, W_hh read directly) + encW MFMA --------
// encW epilogue PRE-SCALES by -2*log2(e) (consumed only by energy's tanh).
__global__ __launch_bounds__(1024, 1) void hchain_enc(
    const float* __restrict__ Xih, const float* __restrict__ W_hh,
    const float* __restrict__ h0,
    float* __restrict__ A_comb, float* __restrict__ h_all,
    const float* __restrict__ encA,
    const unsigned short* __restrict__ Whi, const unsigned short* __restrict__ Wlo,
    const float* __restrict__ bias512, float* __restrict__ encW)
{
  __shared__ __align__(16) unsigned char smem_raw[67584];
  const int tid = threadIdx.x;

  if (blockIdx.x < B) {
    // ---------------- h-chain ----------------
    float* h_s = (float*)smem_raw;        // 256
    float* red = h_s + 256;               // 1024
    const int b = blockIdx.x;
    const int c = tid >> 8, d = tid & 255, k0 = c * 64;
    float wreg[64];
#pragma unroll
    for (int j = 0; j < 64; j += 4) {
      float4 wv = *(const float4*)(W_hh + (size_t)d * E + k0 + j);
      wreg[j] = wv.x; wreg[j + 1] = wv.y; wreg[j + 2] = wv.z; wreg[j + 3] = wv.w;
    }
    if (tid < E) h_s[tid] = h0[(size_t)b * E + tid];
    __syncthreads();
    for (int s = 0; s < T_DEC; ++s) {
      float acc = 0.f;
#pragma unroll
      for (int j = 0; j < 64; j += 4) {
        float4 hh = *(const float4*)&h_s[k0 + j];
        acc += hh.x * wreg[j] + hh.y * wreg[j + 1] + hh.z * wreg[j + 2] + hh.w * wreg[j + 3];
      }
      red[tid] = acc;
      __syncthreads();
      if (tid < E) {
        float v = red[tid] + red[256 + tid] + red[512 + tid] + red[768 + tid]
                + Xih[((size_t)s * B + b) * E + tid];
        float hh = ftanh(v);
        h_s[tid] = hh;
        A_comb[((size_t)(b * T_DEC + s)) * (2 * E) + E + tid] = hh;
        h_all[((size_t)(b * T_DEC + s)) * E + tid] = hh;
      }
      __syncthreads();
    }
  } else {
    // ---------------- encW: 64 rows, 16 waves x 32 cols ----------------
    unsigned short* a_hi = (unsigned short*)smem_raw;       // [64][264]
    unsigned short* a_lo = a_hi + 64 * 264;
    const int row0 = (int)(blockIdx.x - B) * 64;
#pragma unroll
    for (int u = 0; u < 4; ++u) {
      int f = tid + (u << 10);
      int r = f >> 6, cc = (f & 63) << 2;
      float4 v = *(const float4*)(encA + (size_t)(row0 + r) * E + cc);
      ushort4 h, l;
      h.x = f2bf(v.x); l.x = f2bf(v.x - bf2f(h.x));
      h.y = f2bf(v.y); l.y = f2bf(v.y - bf2f(h.y));
      h.z = f2bf(v.z); l.z = f2bf(v.z - bf2f(h.z));
      h.w = f2bf(v.w); l.w = f2bf(v.w - bf2f(h.w));
      *(ushort4*)&a_hi[r * 264 + cc] = h;
      *(ushort4*)&a_lo[r * 264 + cc] = l;
    }
    __syncthreads();
    const int lane = tid & 63, w = tid >> 6;
    const int m = lane & 15, q = lane >> 4;
    const int c0 = w << 5;               // 32 cols per wave
    floatx4 acc[4][2] = {};
    for (int k0 = 0; k0 < E; k0 += 32) {
      const size_t w0 = (size_t)(c0 + m) * E + (q << 3) + k0;
      const size_t w1 = (size_t)(c0 + 16 + m) * E + (q << 3) + k0;
      short8 bh0 = *(const short8*)(Whi + w0);
      short8 bl0 = *(const short8*)(Wlo + w0);
      short8 bh1 = *(const short8*)(Whi + w1);
      short8 bl1 = *(const short8*)(Wlo + w1);
#pragma unroll
      for (int rg = 0; rg < 4; ++rg) {
        short8 ah = *(const short8*)&a_hi[((rg << 4) + m) * 264 + (q << 3) + k0];
        short8 al = *(const short8*)&a_lo[((rg << 4) + m) * 264 + (q << 3) + k0];
        acc[rg][0] = __builtin_amdgcn_mfma_f32_16x16x32_bf16(ah, bh0, acc[rg][0], 0, 0, 0);
        acc[rg][0] = __builtin_amdgcn_mfma_f32_16x16x32_bf16(al, bh0, acc[rg][0], 0, 0, 0);
        acc[rg][0] = __builtin_amdgcn_mfma_f32_16x16x32_bf16(ah, bl0, acc[rg][0], 0, 0, 0);
        acc[rg][0] = __builtin_amdgcn_mfma_f32_16x16x32_bf16(al, bl0, acc[rg][0], 0, 0, 0);
        acc[rg][1] = __builtin_amdgcn_mfma_f32_16x16x32_bf16(ah, bh1, acc[rg][1], 0, 0, 0);
        acc[rg][1] = __builtin_amdgcn_mfma_f32_16x16x32_bf16(al, bh1, acc[rg][1], 0, 0, 0);
        acc[rg][1] = __builtin_amdgcn_mfma_f32_16x16x32_bf16(ah, bl1, acc[rg][1], 0, 0, 0);
        acc[rg][1] = __builtin_amdgcn_mfma_f32_16x16x32_bf16(al, bl1, acc[rg][1], 0, 0, 0);
      }
    }
    const float bia0 = bias512[c0 + m], bia1 = bias512[c0 + 16 + m];
#pragma unroll
    for (int rg = 0; rg < 4; ++rg)
#pragma unroll
      for (int r = 0; r < 4; ++r) {
        const size_t row = row0 + (rg << 4) + (q << 2) + r;
        encW[row * (2 * E) + c0 + m]      = NEG2LOG2E * (acc[rg][0][r] + bia0);
        encW[row * (2 * E) + c0 + 16 + m] = NEG2LOG2E * (acc[rg][1][r] + bia1);
      }
  }
}

// ---------------- energies for ALL (b,s,t): fully parallel ----------------
// Grid (B, 16, 2), 512 threads. Inputs arrive PRE-SCALED; hot loop has no
// scaling ops. Correct two-register multi-value butterfly (== wredsum tree).
__global__ __launch_bounds__(512) void energy_kernel(
    const float* __restrict__ encW, const float* __restrict__ g_hv,
    const float* __restrict__ w_effm, const float* __restrict__ w_effc,
    const float* __restrict__ vbm, const float* __restrict__ rmp,
    const float* __restrict__ vbc, const float* __restrict__ rcp_,
    float* __restrict__ g_pe)
{
  __shared__ float hv_s[16 * 512];   // 32 KB
  const int b = blockIdx.x, t0 = blockIdx.y << 5, s0 = blockIdx.z << 4;
  const int tid = threadIdx.x, lane = tid & 63, w = tid >> 6;
  const float* hvb = g_hv + ((size_t)(b * T_DEC + s0)) * 512;
  for (int i = tid * 4; i < 16 * 512; i += 2048)
    *(float4*)&hv_s[i] = *(const float4*)(hvb + i);
  __syncthreads();

  const float embias = vbm[0] + rmp[0];
  const float ecbias = vbc[0] + rcp_[0];
  const float bias_l = ((lane >> 2) & 1) ? ecbias : embias;
  const float4 wm4 = *(const float4*)(w_effm + lane * 4);
  const float4 wc4 = *(const float4*)(w_effc + lane * 4);
  const int t = t0 + (w << 2);
  const size_t rb = ((size_t)(b * T_ENC + t)) * 512 + lane * 4;
  const float4 em0 = *(const float4*)(encW + rb);
  const float4 em1 = *(const float4*)(encW + rb + 512);
  const float4 em2 = *(const float4*)(encW + rb + 1024);
  const float4 em3 = *(const float4*)(encW + rb + 1536);
  const float4 ec0 = *(const float4*)(encW + rb + 256);
  const float4 ec1 = *(const float4*)(encW + rb + 768);
  const float4 ec2 = *(const float4*)(encW + rb + 1280);
  const float4 ec3 = *(const float4*)(encW + rb + 1792);

  const bool sb0 = lane & 1, sb1 = lane & 2, sb2 = lane & 4;
  const int myr = lane >> 3;     // step residue this lane captures
  float pv0 = 0.f, pv1 = 0.f;

  for (int sl = 0; sl < 16; ++sl) {
    const float4 hm4 = *(const float4*)&hv_s[(sl << 9) + lane * 4];
    const float4 hc4 = *(const float4*)&hv_s[(sl << 9) + 256 + lane * 4];
    float v0 = dot4_wtanh(em0, hm4, wm4);
    float v1 = dot4_wtanh(em1, hm4, wm4);
    float v2 = dot4_wtanh(em2, hm4, wm4);
    float v3 = dot4_wtanh(em3, hm4, wm4);
    float v4 = dot4_wtanh(ec0, hc4, wc4);
    float v5 = dot4_wtanh(ec1, hc4, wc4);
    float v6 = dot4_wtanh(ec2, hc4, wc4);
    float v7 = dot4_wtanh(ec3, hc4, wc4);
    float k0_ = sb0 ? v1 : v0, s0_ = sb0 ? v0 : v1; k0_ += __shfl_xor(s0_, 1, 64);
    float k1_ = sb0 ? v3 : v2, s1_ = sb0 ? v2 : v3; k1_ += __shfl_xor(s1_, 1, 64);
    float k2_ = sb0 ? v5 : v4, s2_ = sb0 ? v4 : v5; k2_ += __shfl_xor(s2_, 1, 64);
    float k3_ = sb0 ? v7 : v6, s3_ = sb0 ? v6 : v7; k3_ += __shfl_xor(s3_, 1, 64);
    float kA = sb1 ? k1_ : k0_, sA = sb1 ? k0_ : k1_; kA += __shfl_xor(sA, 2, 64);
    float kB = sb1 ? k3_ : k2_, sB = sb1 ? k2_ : k3_; kB += __shfl_xor(sB, 2, 64);
    float dd = sb2 ? kB : kA, sD = sb2 ? kA : kB; dd += __shfl_xor(sD, 4, 64);
    dd += __shfl_xor(dd, 8, 64);
    dd += __shfl_xor(dd, 16, 64);
    dd += __shfl_xor(dd, 32, 64);
    float val = dd + bias_l;
    if ((sl & 7) == myr) {
      if (sl & 8) pv1 = val; else pv0 = val;
    }
  }
  const int row_l = lane & 3, type = (lane >> 2) & 1;
  const int tS = t + row_l;
  const int col = type * 32 + s0 + myr;
  g_pe[((size_t)((b << 6) + col)) * 512 + tS]     = pv0;
  g_pe[((size_t)((b << 6) + col + 8)) * 512 + tS] = pv1;
}

// ---------------- alpha/beta recurrence: ONE WAVE per b ----------------
// Writes beta TRANSPOSED: beta_T[b][t][s] (feeds context without staging).
__global__ __launch_bounds__(64) void scan_kernel(
    const float* __restrict__ g_pe, const float* __restrict__ noise,
    float* __restrict__ beta_T)
{
  const int b = blockIdx.x, lane = threadIdx.x;
  const float* pe = g_pe + ((size_t)b << 15);   // b*64*512
  float alpha[8];
#pragma unroll
  for (int i = 0; i < 8; ++i) alpha[i] = 0.f;
  if (lane == 0) alpha[0] = 1.f;

  for (int s = 0; s < T_DEC; ++s) {
    const float* nrow = noise + ((size_t)s * B + b) * T_ENC + lane * 8;
    float4 n0 = *(const float4*)nrow;
    float4 n1 = *(const float4*)(nrow + 4);
    float nz[8] = {n0.x, n0.y, n0.z, n0.w, n1.x, n1.y, n1.z, n1.w};
    const float* psm = pe + (size_t)s * 512 + lane * 8;
    const float* pec = pe + (size_t)(32 + s) * 512 + lane * 8;
    float4 m0 = *(const float4*)psm;
    float4 m1 = *(const float4*)(psm + 4);
    float4 e0 = *(const float4*)pec;
    float4 e1 = *(const float4*)(pec + 4);
    float smv[8] = {m0.x, m0.y, m0.z, m0.w, m1.x, m1.y, m1.z, m1.w};
    float ec[8]  = {e0.x, e0.y, e0.z, e0.w, e1.x, e1.y, e1.z, e1.w};
    float p[8];
#pragma unroll
    for (int i = 0; i < 8; ++i) p[i] = fsigmoid(smv[i] + nz[i]);
    float lgv[8], lci[8], run = 0.f;
#pragma unroll
    for (int i = 0; i < 8; ++i) {
      float omp = fminf(fmaxf(1.f - p[i], 1e-10f), 1.f);
      lgv[i] = __logf(omp);
      run += lgv[i];
      lci[i] = run;
    }
    float mloc = ec[0];
#pragma unroll
    for (int i = 1; i < 8; ++i) mloc = fmaxf(mloc, ec[i]);
    float ex1 = wexcl(run, lane);
    float mx  = wredmax(mloc);
    float cp[8], ao[8], eu[8];
#pragma unroll
    for (int i = 0; i < 8; ++i) {
      float incl = lci[i] + ex1;
      cp[i] = __expf(incl - lgv[i]);               // exclusive cumprod
      float cpc = fminf(fmaxf(cp[i], 1e-10f), 1.f);
      ao[i] = alpha[i] * __builtin_amdgcn_rcpf(cpc);
      eu[i] = __expf(ec[i] - mx);
    }
    float run2 = 0.f, lc2[8], run3 = 0.f, c1[8];
#pragma unroll
    for (int i = 0; i < 8; ++i) {
      run2 += ao[i]; lc2[i] = run2;
      run3 += eu[i]; c1[i] = run3;
    }
    float ex2 = wexcl(run2, lane);
    float ex3 = wexcl(run3, lane);
    float alpha_new[8];
#pragma unroll
    for (int i = 0; i < 8; ++i) {
      alpha_new[i] = p[i] * cp[i] * (lc2[i] + ex2);
      c1[i] += ex3;
    }
    float r[8];
#pragma unroll
    for (int i = 0; i < 8; ++i) {
      float up = __shfl_up(c1[i], 1, 64);
      float prev = (lane == 0) ? 0.f : up;
      float denom = fmaxf(c1[i] - prev, 1e-10f);
      r[i] = alpha_new[i] * __builtin_amdgcn_rcpf(denom);
    }
    float run4 = 0.f, c2[8];
#pragma unroll
    for (int i = 0; i < 8; ++i) { run4 += r[i]; c2[i] = run4; }
    float ex4 = wexcl(run4, lane);
#pragma unroll
    for (int i = 0; i < 8; ++i) c2[i] += ex4;
    float c2_7 = c2[7];
    float dn[8];
#pragma unroll
    for (int i = 0; i < 8; ++i) dn[i] = __shfl_down(c2[i], 1, 64);
    float up7 = __shfl_up(c2_7, 1, 64);
#pragma unroll
    for (int i = 0; i < 8; ++i) {
      float hi = (i == 0) ? c2_7 : ((lane == 63) ? c2_7 : dn[i - 1]);
      float lo = (i == 0) ? ((lane == 0) ? 0.f : up7) : c2[i - 1];
      float beta = eu[i] * (hi - lo);
      beta_T[((size_t)(b * T_ENC) + lane * 8 + i) * T_DEC + s] = beta;
    }
#pragma unroll
    for (int i = 0; i < 8; ++i) alpha[i] = alpha_new[i];
  }
}

// ---------------- context: ctx[b,s,:] = sum_t beta_T[b,t,s] * enc[b,t,:] ---
// Grid (B, 8): 32 e-dims per block, 256 thr, 33.8 KB LDS (conflict-free).
__global__ __launch_bounds__(256) void context_kernel(
    const float* __restrict__ beta_T, const float* __restrict__ enc,
    float* __restrict__ A_comb)
{
  __shared__ float smem[8 * 32 * 33];          // [tg][el][33] padded
  const int b = blockIdx.x, e0 = blockIdx.y << 5;
  const int tid = threadIdx.x;
  const int el = tid & 31, tg = tid >> 5;
  float4 a8[8];
#pragma unroll
  for (int u = 0; u < 8; ++u) a8[u] = (float4){0.f, 0.f, 0.f, 0.f};
  const float* ep = enc + (size_t)b * T_ENC * E + e0 + el;
  const float* bt0 = beta_T + (size_t)b * T_ENC * T_DEC;
  for (int t = tg; t < T_ENC; t += 8) {
    float v = ep[(size_t)t * E];
    const float4* bt = (const float4*)(bt0 + (size_t)t * T_DEC);
#pragma unroll
    for (int u = 0; u < 8; ++u) {
      float4 bv = bt[u];
      a8[u].x += bv.x * v; a8[u].y += bv.y * v;
      a8[u].z += bv.z * v; a8[u].w += bv.w * v;
    }
  }
  float* my = &smem[(tg * 32 + el) * 33];
#pragma unroll
  for (int u = 0; u < 8; ++u) *(float4*)(my + u * 4) = a8[u];
  __syncthreads();
  for (int o = tid; o < 32 * 32; o += 256) {
    int e = o >> 5, s = o & 31;
    float v = 0.f;
#pragma unroll
    for (int g = 0; g < 8; ++g) v += smem[(g * 32 + e) * 33 + s];
    A_comb[((size_t)(b * T_DEC + s)) * (2 * E) + e0 + e] = v;
  }
}

// ---------------- attn = tanh(A_comb[1024,512] @ Wt[512,256]) -> bf16 ------
__global__ __launch_bounds__(256) void comb_tanh_kernel(
    const float* __restrict__ A, const float* __restrict__ Wt,
    unsigned short* __restrict__ attn_bf)
{
  __shared__ float As[64][68];
  __shared__ float Ws[64][68];
  const int tid = threadIdx.x, tx = tid & 15, ty = tid >> 4;
  const int row0 = blockIdx.y * 64, col0 = blockIdx.x * 64;
  float acc[4][4];
#pragma unroll
  for (int i = 0; i < 4; i++)
#pragma unroll
    for (int jj = 0; jj < 4; jj++) acc[i][jj] = 0.f;

  for (int k0 = 0; k0 < 2 * E; k0 += 64) {
#pragma unroll
    for (int ss = 0; ss < 4; ss++) {
      int i = (ss << 4) + ty;
      int jj = tx << 2;
      float4 av = *(const float4*)(A + (size_t)(row0 + i) * (2 * E) + k0 + jj);
      As[jj][i] = av.x; As[jj + 1][i] = av.y; As[jj + 2][i] = av.z; As[jj + 3][i] = av.w;
      float4 wv = *(const float4*)(Wt + (size_t)(k0 + i) * E + col0 + jj);
      *(float4*)&Ws[i][jj] = wv;
    }
    __syncthreads();
#pragma unroll
    for (int kk = 0; kk < 64; kk++) {
      const float4 af = *(const float4*)&As[kk][ty << 2];
      const float4 bf = *(const float4*)&Ws[kk][tx << 2];
      acc[0][0] += af.x * bf.x; acc[0][1] += af.x * bf.y; acc[0][2] += af.x * bf.z; acc[0][3] += af.x * bf.w;
      acc[1][0] += af.y * bf.x; acc[1][1] += af.y * bf.y; acc[1][2] += af.y * bf.z; acc[1][3] += af.y * bf.w;
      acc[2][0] += af.z * bf.x; acc[2][1] += af.z * bf.y; acc[2][2] += af.z * bf.z; acc[2][3] += af.z * bf.w;
      acc[3][0] += af.w * bf.x; acc[3][1] += af.w * bf.y; acc[3][2] += af.w * bf.z; acc[3][3] += af.w * bf.w;
    }
    __syncthreads();
  }
#pragma unroll
  for (int i = 0; i < 4; i++) {
    ushort4 o;
    o.x = f2bf(ftanh(acc[i][0])); o.y = f2bf(ftanh(acc[i][1]));
    o.z = f2bf(ftanh(acc[i][2])); o.w = f2bf(ftanh(acc[i][3]));
    *(ushort4*)(attn_bf + (size_t)(row0 + (ty << 2) + i) * E + col0 + (tx << 2)) = o;
  }
}

// ---------------- projection: (col-panel, M-half) per block ---------------
__global__ __launch_bounds__(256) void proj_mfma(
    const unsigned short* __restrict__ A, const unsigned short* __restrict__ Bw,
    const float* __restrict__ bias, float* __restrict__ Y)
{
  __shared__ unsigned short wl[64][264];   // 33.8 KB
  __shared__ float tile[64][68];           // 17.4 KB
  const int tid = threadIdx.x;
  const int wave = tid >> 6, lane = tid & 63;
  const int m = lane & 15, q = lane >> 4;
  const int col0 = (blockIdx.x >> 1) * 64;
  const int mt0 = (blockIdx.x & 1) * 8;
#pragma unroll
  for (int u = 0; u < 16; ++u) {
    int f = tid + (u << 8);
    int r = f >> 6, c = (f & 63) << 2;
    *(ushort4*)&wl[r][c] = *(const ushort4*)(Bw + (size_t)(col0 + r) * E + c);
  }
  __syncthreads();

  for (int mt = mt0; mt < mt0 + 8; ++mt) {
    const int rowa = mt * 64 + wave * 16;
    floatx4 acc0 = {0.f, 0.f, 0.f, 0.f}, acc1 = acc0, acc2 = acc0, acc3 = acc0;
    const unsigned short* ar = A + (size_t)(rowa + m) * E + q * 8;
#pragma unroll
    for (int k0 = 0; k0 < E; k0 += 32) {
      short8 af = *(const short8*)(ar + k0);
      short8 b0 = *(const short8*)&wl[ 0 + m][q * 8 + k0];
      short8 b1 = *(const short8*)&wl[16 + m][q * 8 + k0];
      short8 b2 = *(const short8*)&wl[32 + m][q * 8 + k0];
      short8 b3 = *(const short8*)&wl[48 + m][q * 8 + k0];
      acc0 = __builtin_amdgcn_mfma_f32_16x16x32_bf16(af, b0, acc0, 0, 0, 0);
      acc1 = __builtin_amdgcn_mfma_f32_16x16x32_bf16(af, b1, acc1, 0, 0, 0);
      acc2 = __builtin_amdgcn_mfma_f32_16x16x32_bf16(af, b2, acc2, 0, 0, 0);
      acc3 = __builtin_amdgcn_mfma_f32_16x16x32_bf16(af, b3, acc3, 0, 0, 0);
    }
    const int rl = wave * 16 + q * 4;
#pragma unroll
    for (int r = 0; r < 4; r++) {
      tile[rl + r][ 0 + m] = acc0[r];
      tile[rl + r][16 + m] = acc1[r];
      tile[rl + r][32 + m] = acc2[r];
      tile[rl + r][48 + m] = acc3[r];
    }
    __syncthreads();
    const int row = tid >> 2, seg = tid & 3;
    const size_t yb = ((size_t)mt * 64 + row) * VOCAB + col0;
#pragma unroll
    for (int u = 0; u < 4; u++) {
      int cc = seg * 16 + u * 4;
      float4 v = *(const float4*)&tile[row][cc];
      float4 bb = *(const float4*)(bias + col0 + cc);
      v.x += bb.x; v.y += bb.y; v.z += bb.z; v.w += bb.w;
      *(float4*)(Y + yb + cc) = v;
    }
    __syncthreads();
  }
}

// ---------------- launch ----------------
extern "C" void kernel_launch(void* const* d_in, const int* in_sizes, int n_in,
                              void* d_out, int out_size, void* d_ws, size_t ws_size,
                              hipStream_t stream)
{
  (void)in_sizes; (void)n_in; (void)out_size; (void)ws_size;
  const float* enc    = (const float*)d_in[0];
  const int*   dec    = (const int*)d_in[1];
  const float* h0     = (const float*)d_in[2];
  const float* noise  = (const float*)d_in[3];
  const float* emb    = (const float*)d_in[4];
  const float* W_ih   = (const float*)d_in[5];
  const float* b_ih   = (const float*)d_in[6];
  const float* W_hh   = (const float*)d_in[7];
  const float* b_hh   = (const float*)d_in[8];
  const float* Wm     = (const float*)d_in[9];
  const float* Vm     = (const float*)d_in[10];
  const float* bm     = (const float*)d_in[11];
  const float* vvm    = (const float*)d_in[12];
  const float* gm     = (const float*)d_in[13];
  const float* vbm    = (const float*)d_in[14];
  const float* rmp    = (const float*)d_in[15];
  const float* Wc     = (const float*)d_in[16];
  const float* Vc     = (const float*)d_in[17];
  const float* bc     = (const float*)d_in[18];
  const float* vvc    = (const float*)d_in[19];
  const float* gc     = (const float*)d_in[20];
  const float* vbc    = (const float*)d_in[21];
  const float* rcp_   = (const float*)d_in[22];
  const float* W_comb = (const float*)d_in[23];
  const float* W_proj = (const float*)d_in[24];
  const float* b_proj = (const float*)d_in[25];

  float* ws = (float*)d_ws;
  float* encW    = ws + OFF_ENCW;
  float* w_effm  = ws + OFF_WEFFM;
  float* w_effc  = ws + OFF_WEFFC;
  float* Xih     = ws + OFF_XIH;
  float* W_combT = ws + OFF_WCOMBT;
  unsigned short* attn_bf = (unsigned short*)(ws + OFF_ATTNB);
  unsigned short* Wp_bf   = (unsigned short*)(ws + OFF_WPBF);

  float* outF = (float*)d_out;
  float* beta_T   = outF + OUT_BETA;     // scratch in d_out, all consumed
  float* A_comb   = outF + OUT_ACOMB;    //   before proj_mfma overwrites it
  float* h_all    = outF + OUT_HALL;
  float* g_hv     = outF + OUT_HV;
  float* g_pe     = outF + OUT_PE;
  float* Vmc      = outF + OUT_VMC;
  float* zero512  = outF + OUT_ZERO;
  unsigned short* Whi = (unsigned short*)(outF + OUT_WHI);
  unsigned short* Wlo = (unsigned short*)(outF + OUT_WLO);
  float* bias512  = outF + OUT_B512;

  // 1. all step-invariant prep + Xih gemm (gather inline) in ONE launch
  prep_all<<<8451, 256, 0, stream>>>(dec, emb, W_ih, b_ih, b_hh, Xih,
                                     vvm, gm, w_effm, vvc, gc, w_effc,
                                     bm, bc, bias512, Vm, Vc, Vmc, zero512,
                                     Wm, Wc, Whi, Wlo, W_comb, W_combT,
                                     W_proj, Wp_bf);
  // 2. h-chain (W_hh direct) + encW MFMA (pre-scaled epilogue) concurrently
  hchain_enc<<<B + (B * T_ENC) / 64, 1024, 0, stream>>>(
      Xih, W_hh, h0, A_comb, h_all, enc, Whi, Wlo, bias512, encW);
  // 3. hV = -2log2e * ([Vm;Vc] h) for all (b,s)
  gemm_xwt<<<dim3((2 * E) / 64, (T_DEC * B) / 64), 256, 0, stream>>>(
      h_all, Vmc, zero512, g_hv, T_DEC * B, 2 * E, E, NEG2LOG2E);
  // 4. energies (pre-scaled inputs, exp2 hot loop)
  energy_kernel<<<dim3(B, 16, 2), 512, 0, stream>>>(
      encW, g_hv, w_effm, w_effc, vbm, rmp, vbc, rcp_, g_pe);
  // 5. alpha/beta scans -> beta_T
  scan_kernel<<<B, 64, 0, stream>>>(g_pe, noise, beta_T);
  // 6-8. context, attn, projection
  context_kernel<<<dim3(B, 8), 256, 0, stream>>>(beta_T, enc, A_comb);
  comb_tanh_kernel<<<dim3(E / 64, (T_DEC * B) / 64), 256, 0, stream>>>(A_comb, W_combT, attn_bf);
  proj_mfma<<<2 * (VOCAB / 64), 256, 0, stream>>>(attn_bf, Wp_bf, b_proj, outF);
}